// Round 13
// baseline (197.868 us; speedup 1.0000x reference)
//
#include <hip/hip_runtime.h>

#define NN 12000
#define FF 128
#define HH 32
#define CAP 96     // adjacency capacity (deg mean 33, std 5.7)
#define NBIN 64    // pool atomic bins
#define NB4 (NN / 4)   // 3000 per-node blocks

typedef unsigned int uintv4 __attribute__((ext_vector_type(4)));

// ---------------------------------------------------------------------------
// Kernel 1 (heterogeneous blocks): 15000 blocks, groups of 5 = 4 scan rows +
// 1 xw1 block (4 nodes). Scan path == round-8 verified body; xw1 path uses
// only ~3 KB LDS and reads W1 from L2 (scan occupancy preserved).
//   scan: dense a-row -> adj (u16) + deg          [HBM-bound, 576 MB]
//   xw1:  Z = x @ W1_top, Y = x @ W1_bot          [overlaps the scan]
// Block 0 zeroes the pool bins + done counter (replay-safe).
// ---------------------------------------------------------------------------
__global__ __launch_bounds__(256) void k_scanx(const float* __restrict__ a,
    const float* __restrict__ x, const float* __restrict__ W1,
    unsigned short* __restrict__ adj, int* __restrict__ deg,
    float* __restrict__ Z, float* __restrict__ Y,
    float* __restrict__ partial, int* __restrict__ ctrl) {
  const int b = blockIdx.x, tid = threadIdx.x;
  const int g5 = b / 5, m = b % 5;
  __shared__ int cnt;
  __shared__ unsigned short slist[CAP];
  __shared__ float sx[4][FF];
  __shared__ float sacc[4][64];

  if (b == 0) {
    for (int i = tid; i < NBIN * HH; i += 256) partial[i] = 0.f;
    if (tid == 0) ctrl[0] = 0;
  }

  if (m == 4) {
    // ---------------- xw1 path: nodes 4*g5 .. 4*g5+3 ----------------
    const int n0 = 4 * g5;
    for (int i = tid; i < 4 * FF; i += 256)
      sx[i >> 7][i & (FF - 1)] = x[(size_t)(n0 + (i >> 7)) * FF + (i & (FF - 1))];
    __syncthreads();
    const int j = tid & 31;              // output col within half
    const int half = (tid >> 5) & 1;     // 0 -> Z, 1 -> Y
    const int ch = tid >> 6;             // f-chunk
    const float* Wb = W1 + (size_t)(half * FF) * HH;
    #pragma unroll
    for (int nn = 0; nn < 4; ++nn) {
      float acc = 0.f;
      const int f0 = ch * 32;
      #pragma unroll 8
      for (int f = f0; f < f0 + 32; ++f)
        acc += sx[nn][f] * Wb[f * HH + j];
      sacc[ch][tid & 63] = acc;
      __syncthreads();
      if (tid < 64) {
        float o = (sacc[0][tid] + sacc[1][tid]) + (sacc[2][tid] + sacc[3][tid]);
        if (tid < HH) Z[(size_t)(n0 + nn) * HH + tid] = o;
        else          Y[(size_t)(n0 + nn) * HH + (tid - HH)] = o;
      }
      __syncthreads();
    }
    return;
  }

  // ---------------- scan path: row = 4*g5 + m (round-8 exact) ----------------
  const int row = 4 * g5 + m;
  if (tid == 0) cnt = 0;
  __syncthreads();

  const uintv4* arow = (const uintv4*)(a + (size_t)row * NN);
  uintv4 v[12];
  #pragma unroll
  for (int i = 0; i < 12; ++i) {
    const int c = tid + i * 256;
    uintv4 z = {0u, 0u, 0u, 0u};
    v[i] = (c < NN / 4) ? arow[c] : z;
  }
  #pragma unroll
  for (int i = 0; i < 12; ++i) {
    const int c = tid + i * 256;
    uintv4 w = v[i];
    if ((w.x | w.y | w.z | w.w) == 0u) continue;
    int j0 = 4 * c;
    if (w.x && j0     != row) { int p = atomicAdd(&cnt, 1); if (p < CAP-1) slist[p] = (unsigned short)(j0    ); }
    if (w.y && j0 + 1 != row) { int p = atomicAdd(&cnt, 1); if (p < CAP-1) slist[p] = (unsigned short)(j0 + 1); }
    if (w.z && j0 + 2 != row) { int p = atomicAdd(&cnt, 1); if (p < CAP-1) slist[p] = (unsigned short)(j0 + 2); }
    if (w.w && j0 + 3 != row) { int p = atomicAdd(&cnt, 1); if (p < CAP-1) slist[p] = (unsigned short)(j0 + 3); }
  }
  __syncthreads();
  const int c = min(cnt, CAP - 1);
  if (tid == 0) { slist[c] = (unsigned short)row; deg[row] = c + 1; }  // self loop
  __syncthreads();
  if (tid < c + 1) adj[(size_t)row * CAP + tid] = slist[tid];
}

// ---------------------------------------------------------------------------
// Kernel 2: layer 1 gather-only: h1 = tanh(l2n(Z_i + (Sum_j Y_j)/d + b1)).
// Gather unrolled x8 (8 independent loads in flight per lane).
// ---------------------------------------------------------------------------
__global__ __launch_bounds__(256) void k_gl1(const float* __restrict__ Z,
    const float* __restrict__ Y, const float* __restrict__ b,
    const unsigned short* __restrict__ adj, const int* __restrict__ deg,
    float* __restrict__ hout) {
  __shared__ unsigned short sidx[4][CAP];
  const int tid = threadIdx.x;
  const int wave = tid >> 6, lane = tid & 63;
  const int k = lane & 31, g = lane >> 5;
  const int node = blockIdx.x * 4 + wave;
  const int d = deg[node];
  for (int n = lane; n < d; n += 64)
    sidx[wave][n] = adj[(size_t)node * CAP + n];
  __syncthreads();

  float p0 = 0.f, p1 = 0.f, p2 = 0.f, p3 = 0.f;
  float q0 = 0.f, q1 = 0.f, q2 = 0.f, q3 = 0.f;
  int n = g;
  for (; n + 14 < d; n += 16) {        // stride-2 per half, unroll x8
    p0 += Y[(size_t)sidx[wave][n     ] * HH + k];
    p1 += Y[(size_t)sidx[wave][n +  2] * HH + k];
    p2 += Y[(size_t)sidx[wave][n +  4] * HH + k];
    p3 += Y[(size_t)sidx[wave][n +  6] * HH + k];
    q0 += Y[(size_t)sidx[wave][n +  8] * HH + k];
    q1 += Y[(size_t)sidx[wave][n + 10] * HH + k];
    q2 += Y[(size_t)sidx[wave][n + 12] * HH + k];
    q3 += Y[(size_t)sidx[wave][n + 14] * HH + k];
  }
  for (; n < d; n += 2)
    p0 += Y[(size_t)sidx[wave][n] * HH + k];
  float agg = ((p0 + p1) + (p2 + p3)) + ((q0 + q1) + (q2 + q3));
  agg += __shfl_xor(agg, 32);
  agg *= 1.0f / (float)d;
  float o = Z[(size_t)node * HH + k] + agg + b[k];
  float ss = o * o;
  for (int off = 16; off; off >>= 1) ss += __shfl_xor(ss, off, 32);
  float r = rsqrtf(fmaxf(ss, 1e-12f));
  if (lane < 32) hout[(size_t)node * HH + k] = tanhf(o * r);
}

// ---------------------------------------------------------------------------
// Kernel 3: SAGE layer 2 (round-8 body, gather unroll x8).
// ---------------------------------------------------------------------------
__global__ __launch_bounds__(256) void k_sageh(const float* __restrict__ hin,
    const float* __restrict__ W, const float* __restrict__ b,
    const unsigned short* __restrict__ adj, const int* __restrict__ deg,
    float* __restrict__ hout) {
  __shared__ float sW[2 * HH * HH];
  __shared__ float sb[HH];
  __shared__ float sbuf[4][2 * HH];
  __shared__ unsigned short sidx[4][CAP];
  const int tid = threadIdx.x;
  for (int i = tid; i < 2 * HH * HH; i += 256) sW[i] = W[i];
  if (tid < HH) sb[tid] = b[tid];

  const int wave = tid >> 6, lane = tid & 63;
  const int k = lane & 31, g = lane >> 5;
  const int node = blockIdx.x * 4 + wave;
  const int d = deg[node];
  for (int n = lane; n < d; n += 64)
    sidx[wave][n] = adj[(size_t)node * CAP + n];
  __syncthreads();

  float p0 = 0.f, p1 = 0.f, p2 = 0.f, p3 = 0.f;
  float q0 = 0.f, q1 = 0.f, q2 = 0.f, q3 = 0.f;
  int n = g;
  for (; n + 14 < d; n += 16) {
    p0 += hin[(size_t)sidx[wave][n     ] * HH + k];
    p1 += hin[(size_t)sidx[wave][n +  2] * HH + k];
    p2 += hin[(size_t)sidx[wave][n +  4] * HH + k];
    p3 += hin[(size_t)sidx[wave][n +  6] * HH + k];
    q0 += hin[(size_t)sidx[wave][n +  8] * HH + k];
    q1 += hin[(size_t)sidx[wave][n + 10] * HH + k];
    q2 += hin[(size_t)sidx[wave][n + 12] * HH + k];
    q3 += hin[(size_t)sidx[wave][n + 14] * HH + k];
  }
  for (; n < d; n += 2)
    p0 += hin[(size_t)sidx[wave][n] * HH + k];
  float agg = ((p0 + p1) + (p2 + p3)) + ((q0 + q1) + (q2 + q3));
  agg += __shfl_xor(agg, 32);
  agg *= 1.0f / (float)d;
  float hi = hin[(size_t)node * HH + k];
  if (g == 0) { sbuf[wave][k] = hi; sbuf[wave][HH + k] = agg; }
  __syncthreads();

  float acc = 0.f;
  const float* bufh = sbuf[wave];
  const int f0 = g * 16;
  #pragma unroll
  for (int f = f0; f < f0 + 16; ++f) {
    acc += bufh[f]      * sW[f * HH + k];
    acc += bufh[HH + f] * sW[(HH + f) * HH + k];
  }
  acc += __shfl_xor(acc, 32);
  acc += sb[k];
  float ss = acc * acc;
  for (int off = 16; off; off >>= 1) ss += __shfl_xor(ss, off, 32);
  float r = rsqrtf(fmaxf(ss, 1e-12f));
  if (lane < 32) hout[(size_t)node * HH + k] = tanhf(acc * r);
}

// ---------------------------------------------------------------------------
// Kernel 4: SAGE layer 3 + pool + (last block) head. Ordering via ACQ_REL
// atomic done-counter ONLY — no __threadfence (that was the r9/r11 +32 us).
// Pool writes are atomics (coherent point), so release = s_waitcnt, not
// an L2 writeback-invalidate.
// ---------------------------------------------------------------------------
__global__ __launch_bounds__(256) void k_sageh3(const float* __restrict__ hin,
    const float* __restrict__ W, const float* __restrict__ b,
    const unsigned short* __restrict__ adj, const int* __restrict__ deg,
    float* __restrict__ partial, int* __restrict__ ctrl,
    const float* __restrict__ Wf1, const float* __restrict__ bf1,
    const float* __restrict__ Wf2, const float* __restrict__ bf2,
    float* __restrict__ out) {
  __shared__ float sW[2 * HH * HH];
  __shared__ float sb[HH];
  __shared__ float sbuf[4][2 * HH];
  __shared__ float red[8][HH];
  __shared__ float sp[HH];
  __shared__ unsigned short sidx[4][CAP];
  __shared__ int amLast;
  const int tid = threadIdx.x;
  for (int i = tid; i < 2 * HH * HH; i += 256) sW[i] = W[i];
  if (tid < HH) sb[tid] = b[tid];

  const int wave = tid >> 6, lane = tid & 63;
  const int k = lane & 31, g = lane >> 5;
  const int node = blockIdx.x * 4 + wave;
  const int d = deg[node];
  for (int n = lane; n < d; n += 64)
    sidx[wave][n] = adj[(size_t)node * CAP + n];
  __syncthreads();

  float p0 = 0.f, p1 = 0.f, p2 = 0.f, p3 = 0.f;
  float q0 = 0.f, q1 = 0.f, q2 = 0.f, q3 = 0.f;
  int n = g;
  for (; n + 14 < d; n += 16) {
    p0 += hin[(size_t)sidx[wave][n     ] * HH + k];
    p1 += hin[(size_t)sidx[wave][n +  2] * HH + k];
    p2 += hin[(size_t)sidx[wave][n +  4] * HH + k];
    p3 += hin[(size_t)sidx[wave][n +  6] * HH + k];
    q0 += hin[(size_t)sidx[wave][n +  8] * HH + k];
    q1 += hin[(size_t)sidx[wave][n + 10] * HH + k];
    q2 += hin[(size_t)sidx[wave][n + 12] * HH + k];
    q3 += hin[(size_t)sidx[wave][n + 14] * HH + k];
  }
  for (; n < d; n += 2)
    p0 += hin[(size_t)sidx[wave][n] * HH + k];
  float agg = ((p0 + p1) + (p2 + p3)) + ((q0 + q1) + (q2 + q3));
  agg += __shfl_xor(agg, 32);
  agg *= 1.0f / (float)d;
  float hi = hin[(size_t)node * HH + k];
  if (g == 0) { sbuf[wave][k] = hi; sbuf[wave][HH + k] = agg; }
  __syncthreads();

  float acc = 0.f;
  const float* bufh = sbuf[wave];
  const int f0 = g * 16;
  #pragma unroll
  for (int f = f0; f < f0 + 16; ++f) {
    acc += bufh[f]      * sW[f * HH + k];
    acc += bufh[HH + f] * sW[(HH + f) * HH + k];
  }
  acc += __shfl_xor(acc, 32);
  acc += sb[k];
  float ss = acc * acc;
  for (int off = 16; off; off >>= 1) ss += __shfl_xor(ss, off, 32);
  float r = rsqrtf(fmaxf(ss, 1e-12f));
  if (lane < 32) red[wave][k] = tanhf(acc * r);
  __syncthreads();
  if (tid < HH) {
    float t = (red[0][tid] + red[1][tid]) + (red[2][tid] + red[3][tid]);
    atomicAdd(&partial[(blockIdx.x & (NBIN - 1)) * HH + tid], t);
  }
  __syncthreads();
  if (tid == 0) {
    amLast = (__hip_atomic_fetch_add(ctrl, 1, __ATOMIC_ACQ_REL,
                                     __HIP_MEMORY_SCOPE_AGENT) == NB4 - 1) ? 1 : 0;
  }
  __syncthreads();
  if (!amLast) return;

  // last block: bins complete (acquire on the counter); read via relaxed
  // agent atomic loads (bypass L1; values live at the coherent point).
  {
    const int col = tid & 31, ch = tid >> 5;   // 8 chunks x 8 bins
    float s = 0.f;
    for (int bb = ch; bb < NBIN; bb += 8)
      s += __hip_atomic_load(&partial[bb * HH + col], __ATOMIC_RELAXED,
                             __HIP_MEMORY_SCOPE_AGENT);
    red[ch][col] = s;
  }
  __syncthreads();
  if (tid < HH) {
    float t = 0.f;
    #pragma unroll
    for (int c2 = 0; c2 < 8; ++c2) t += red[c2][tid];
    sp[tid] = t;
  }
  __syncthreads();
  if (tid < 64) {
    float q = bf1[tid];
    #pragma unroll
    for (int f = 0; f < HH; ++f) q += sp[f] * Wf1[f * 64 + tid];
    q = tanhf(q);
    float rs = q * Wf2[tid];
    for (int off = 32; off; off >>= 1) rs += __shfl_xor(rs, off);
    if (tid == 0) out[0] = rs + bf2[0];
  }
}

// ---------------------------------------------------------------------------
extern "C" void kernel_launch(void* const* d_in, const int* in_sizes, int n_in,
                              void* d_out, int out_size, void* d_ws, size_t ws_size,
                              hipStream_t stream) {
  const float* x   = (const float*)d_in[0];
  const float* a   = (const float*)d_in[1];
  const float* W1  = (const float*)d_in[2];
  const float* b1  = (const float*)d_in[3];
  const float* W2  = (const float*)d_in[4];
  const float* b2  = (const float*)d_in[5];
  const float* W3  = (const float*)d_in[6];
  const float* b3  = (const float*)d_in[7];
  const float* Wf1 = (const float*)d_in[8];
  const float* bf1 = (const float*)d_in[9];
  const float* Wf2 = (const float*)d_in[10];
  const float* bf2 = (const float*)d_in[11];

  char* ws = (char*)d_ws;
  unsigned short* adj = (unsigned short*)ws;  ws += (size_t)NN * CAP * sizeof(unsigned short); // 2.30 MB
  int*   deg     = (int*)ws;                  ws += (size_t)((NN * sizeof(int) + 255) & ~(size_t)255);
  float* Zb      = (float*)ws;                ws += (size_t)NN * HH * sizeof(float);
  float* Yb      = (float*)ws;                ws += (size_t)NN * HH * sizeof(float);
  float* h1      = (float*)ws;                ws += (size_t)NN * HH * sizeof(float);
  float* h2      = (float*)ws;                ws += (size_t)NN * HH * sizeof(float);
  float* partial = (float*)ws;                ws += (size_t)NBIN * HH * sizeof(float);
  int*   ctrl    = (int*)ws;

  hipLaunchKernelGGL(k_scanx,  dim3(NN + NB4), dim3(256), 0, stream,
                     a, x, W1, adj, deg, Zb, Yb, partial, ctrl);
  hipLaunchKernelGGL(k_gl1,    dim3(NB4), dim3(256), 0, stream, Zb, Yb, b1, adj, deg, h1);
  hipLaunchKernelGGL(k_sageh,  dim3(NB4), dim3(256), 0, stream, h1, W2, b2, adj, deg, h2);
  hipLaunchKernelGGL(k_sageh3, dim3(NB4), dim3(256), 0, stream,
                     h2, W3, b3, adj, deg, partial, ctrl, Wf1, bf1, Wf2, bf2, (float*)d_out);
}

// Round 14
// 145.374 us; speedup vs baseline: 1.3611x; 1.3611x over previous
//
#include <hip/hip_runtime.h>

#define NN 12000
#define FF 128
#define HH 32
#define CAP 96     // adjacency capacity (deg mean 33, std 5.7)
#define NBIN 64    // pool atomic bins
#define NB4 (NN / 4)   // 3000 per-node blocks

typedef unsigned int uintv4 __attribute__((ext_vector_type(4)));

// ---------------------------------------------------------------------------
// Kernel 1 (heterogeneous blocks): 15000 blocks, groups of 5 = 4 scan rows +
// 1 xw1 block (4 nodes). Scan path == round-8 verified body; xw1 path uses
// only ~3 KB LDS and reads W1 from L2 (scan occupancy preserved).
//   scan: dense a-row -> adj (u16) + deg          [HBM-bound, 576 MB]
//   xw1:  Z = x @ W1_top, Y = x @ W1_bot          [overlaps the scan]
// Block 0 zeroes the pool bins (replay-safe).
// NOTE (r6/r9/r11/r13 lessons): NO cross-block sync primitives anywhere —
// every agent-scope fence/acquire/release variant costs +30..+52 us via
// L2 invalidate storms on this XCD-partitioned cache hierarchy.
// ---------------------------------------------------------------------------
__global__ __launch_bounds__(256) void k_scanx(const float* __restrict__ a,
    const float* __restrict__ x, const float* __restrict__ W1,
    unsigned short* __restrict__ adj, int* __restrict__ deg,
    float* __restrict__ Z, float* __restrict__ Y,
    float* __restrict__ partial) {
  const int b = blockIdx.x, tid = threadIdx.x;
  const int g5 = b / 5, m = b % 5;
  __shared__ int cnt;
  __shared__ unsigned short slist[CAP];
  __shared__ float sx[4][FF];
  __shared__ float sacc[4][64];

  if (b == 0) {
    for (int i = tid; i < NBIN * HH; i += 256) partial[i] = 0.f;
  }

  if (m == 4) {
    // ---------------- xw1 path: nodes 4*g5 .. 4*g5+3 ----------------
    const int n0 = 4 * g5;
    for (int i = tid; i < 4 * FF; i += 256)
      sx[i >> 7][i & (FF - 1)] = x[(size_t)(n0 + (i >> 7)) * FF + (i & (FF - 1))];
    __syncthreads();
    const int j = tid & 31;              // output col within half
    const int half = (tid >> 5) & 1;     // 0 -> Z, 1 -> Y
    const int ch = tid >> 6;             // f-chunk
    const float* Wb = W1 + (size_t)(half * FF) * HH;
    #pragma unroll
    for (int nn = 0; nn < 4; ++nn) {
      float acc = 0.f;
      const int f0 = ch * 32;
      #pragma unroll 8
      for (int f = f0; f < f0 + 32; ++f)
        acc += sx[nn][f] * Wb[f * HH + j];
      sacc[ch][tid & 63] = acc;
      __syncthreads();
      if (tid < 64) {
        float o = (sacc[0][tid] + sacc[1][tid]) + (sacc[2][tid] + sacc[3][tid]);
        if (tid < HH) Z[(size_t)(n0 + nn) * HH + tid] = o;
        else          Y[(size_t)(n0 + nn) * HH + (tid - HH)] = o;
      }
      __syncthreads();
    }
    return;
  }

  // ---------------- scan path: row = 4*g5 + m (round-8 exact) ----------------
  const int row = 4 * g5 + m;
  if (tid == 0) cnt = 0;
  __syncthreads();

  const uintv4* arow = (const uintv4*)(a + (size_t)row * NN);
  uintv4 v[12];
  #pragma unroll
  for (int i = 0; i < 12; ++i) {
    const int c = tid + i * 256;
    uintv4 z = {0u, 0u, 0u, 0u};
    v[i] = (c < NN / 4) ? arow[c] : z;
  }
  #pragma unroll
  for (int i = 0; i < 12; ++i) {
    const int c = tid + i * 256;
    uintv4 w = v[i];
    if ((w.x | w.y | w.z | w.w) == 0u) continue;
    int j0 = 4 * c;
    if (w.x && j0     != row) { int p = atomicAdd(&cnt, 1); if (p < CAP-1) slist[p] = (unsigned short)(j0    ); }
    if (w.y && j0 + 1 != row) { int p = atomicAdd(&cnt, 1); if (p < CAP-1) slist[p] = (unsigned short)(j0 + 1); }
    if (w.z && j0 + 2 != row) { int p = atomicAdd(&cnt, 1); if (p < CAP-1) slist[p] = (unsigned short)(j0 + 2); }
    if (w.w && j0 + 3 != row) { int p = atomicAdd(&cnt, 1); if (p < CAP-1) slist[p] = (unsigned short)(j0 + 3); }
  }
  __syncthreads();
  const int c = min(cnt, CAP - 1);
  if (tid == 0) { slist[c] = (unsigned short)row; deg[row] = c + 1; }  // self loop
  __syncthreads();
  if (tid < c + 1) adj[(size_t)row * CAP + tid] = slist[tid];
}

// ---------------------------------------------------------------------------
// Kernel 2: layer 1 gather-only: h1 = tanh(l2n(Z_i + (Sum_j Y_j)/d + b1)).
// (round-8 exact)
// ---------------------------------------------------------------------------
__global__ __launch_bounds__(256) void k_gl1(const float* __restrict__ Z,
    const float* __restrict__ Y, const float* __restrict__ b,
    const unsigned short* __restrict__ adj, const int* __restrict__ deg,
    float* __restrict__ hout) {
  __shared__ unsigned short sidx[4][CAP];
  const int tid = threadIdx.x;
  const int wave = tid >> 6, lane = tid & 63;
  const int k = lane & 31, g = lane >> 5;
  const int node = blockIdx.x * 4 + wave;
  const int d = deg[node];
  for (int n = lane; n < d; n += 64)
    sidx[wave][n] = adj[(size_t)node * CAP + n];
  __syncthreads();

  float p0 = 0.f, p1 = 0.f, p2 = 0.f, p3 = 0.f;
  int n = g;
  for (; n + 6 < d; n += 8) {
    p0 += Y[(size_t)sidx[wave][n    ] * HH + k];
    p1 += Y[(size_t)sidx[wave][n + 2] * HH + k];
    p2 += Y[(size_t)sidx[wave][n + 4] * HH + k];
    p3 += Y[(size_t)sidx[wave][n + 6] * HH + k];
  }
  for (; n < d; n += 2)
    p0 += Y[(size_t)sidx[wave][n] * HH + k];
  float agg = (p0 + p1) + (p2 + p3);
  agg += __shfl_xor(agg, 32);
  agg *= 1.0f / (float)d;
  float o = Z[(size_t)node * HH + k] + agg + b[k];
  float ss = o * o;
  for (int off = 16; off; off >>= 1) ss += __shfl_xor(ss, off, 32);
  float r = rsqrtf(fmaxf(ss, 1e-12f));
  if (lane < 32) hout[(size_t)node * HH + k] = tanhf(o * r);
}

// ---------------------------------------------------------------------------
// Kernel 3: SAGE layer 2 (round-8 exact).
// ---------------------------------------------------------------------------
__global__ __launch_bounds__(256) void k_sageh(const float* __restrict__ hin,
    const float* __restrict__ W, const float* __restrict__ b,
    const unsigned short* __restrict__ adj, const int* __restrict__ deg,
    float* __restrict__ hout) {
  __shared__ float sW[2 * HH * HH];
  __shared__ float sb[HH];
  __shared__ float sbuf[4][2 * HH];
  __shared__ unsigned short sidx[4][CAP];
  const int tid = threadIdx.x;
  for (int i = tid; i < 2 * HH * HH; i += 256) sW[i] = W[i];
  if (tid < HH) sb[tid] = b[tid];

  const int wave = tid >> 6, lane = tid & 63;
  const int k = lane & 31, g = lane >> 5;
  const int node = blockIdx.x * 4 + wave;
  const int d = deg[node];
  for (int n = lane; n < d; n += 64)
    sidx[wave][n] = adj[(size_t)node * CAP + n];
  __syncthreads();

  float p0 = 0.f, p1 = 0.f, p2 = 0.f, p3 = 0.f;
  int n = g;
  for (; n + 6 < d; n += 8) {
    p0 += hin[(size_t)sidx[wave][n    ] * HH + k];
    p1 += hin[(size_t)sidx[wave][n + 2] * HH + k];
    p2 += hin[(size_t)sidx[wave][n + 4] * HH + k];
    p3 += hin[(size_t)sidx[wave][n + 6] * HH + k];
  }
  for (; n < d; n += 2)
    p0 += hin[(size_t)sidx[wave][n] * HH + k];
  float agg = (p0 + p1) + (p2 + p3);
  agg += __shfl_xor(agg, 32);
  agg *= 1.0f / (float)d;
  float hi = hin[(size_t)node * HH + k];
  if (g == 0) { sbuf[wave][k] = hi; sbuf[wave][HH + k] = agg; }
  __syncthreads();

  float acc = 0.f;
  const float* bufh = sbuf[wave];
  const int f0 = g * 16;
  #pragma unroll
  for (int f = f0; f < f0 + 16; ++f) {
    acc += bufh[f]      * sW[f * HH + k];
    acc += bufh[HH + f] * sW[(HH + f) * HH + k];
  }
  acc += __shfl_xor(acc, 32);
  acc += sb[k];
  float ss = acc * acc;
  for (int off = 16; off; off >>= 1) ss += __shfl_xor(ss, off, 32);
  float r = rsqrtf(fmaxf(ss, 1e-12f));
  if (lane < 32) hout[(size_t)node * HH + k] = tanhf(acc * r);
}

// ---------------------------------------------------------------------------
// Kernel 4: SAGE layer 3 + fused pool via f32 atomics (round-8 exact: no
// fence, no head — head stays a separate kernel).
// ---------------------------------------------------------------------------
__global__ __launch_bounds__(256) void k_sageh3(const float* __restrict__ hin,
    const float* __restrict__ W, const float* __restrict__ b,
    const unsigned short* __restrict__ adj, const int* __restrict__ deg,
    float* __restrict__ partial) {
  __shared__ float sW[2 * HH * HH];
  __shared__ float sb[HH];
  __shared__ float sbuf[4][2 * HH];
  __shared__ float red[4][HH];
  __shared__ unsigned short sidx[4][CAP];
  const int tid = threadIdx.x;
  for (int i = tid; i < 2 * HH * HH; i += 256) sW[i] = W[i];
  if (tid < HH) sb[tid] = b[tid];

  const int wave = tid >> 6, lane = tid & 63;
  const int k = lane & 31, g = lane >> 5;
  const int node = blockIdx.x * 4 + wave;
  const int d = deg[node];
  for (int n = lane; n < d; n += 64)
    sidx[wave][n] = adj[(size_t)node * CAP + n];
  __syncthreads();

  float p0 = 0.f, p1 = 0.f, p2 = 0.f, p3 = 0.f;
  int n = g;
  for (; n + 6 < d; n += 8) {
    p0 += hin[(size_t)sidx[wave][n    ] * HH + k];
    p1 += hin[(size_t)sidx[wave][n + 2] * HH + k];
    p2 += hin[(size_t)sidx[wave][n + 4] * HH + k];
    p3 += hin[(size_t)sidx[wave][n + 6] * HH + k];
  }
  for (; n < d; n += 2)
    p0 += hin[(size_t)sidx[wave][n] * HH + k];
  float agg = (p0 + p1) + (p2 + p3);
  agg += __shfl_xor(agg, 32);
  agg *= 1.0f / (float)d;
  float hi = hin[(size_t)node * HH + k];
  if (g == 0) { sbuf[wave][k] = hi; sbuf[wave][HH + k] = agg; }
  __syncthreads();

  float acc = 0.f;
  const float* bufh = sbuf[wave];
  const int f0 = g * 16;
  #pragma unroll
  for (int f = f0; f < f0 + 16; ++f) {
    acc += bufh[f]      * sW[f * HH + k];
    acc += bufh[HH + f] * sW[(HH + f) * HH + k];
  }
  acc += __shfl_xor(acc, 32);
  acc += sb[k];
  float ss = acc * acc;
  for (int off = 16; off; off >>= 1) ss += __shfl_xor(ss, off, 32);
  float r = rsqrtf(fmaxf(ss, 1e-12f));
  if (lane < 32) red[wave][k] = tanhf(acc * r);
  __syncthreads();
  if (tid < HH) {
    float t = (red[0][tid] + red[1][tid]) + (red[2][tid] + red[3][tid]);
    atomicAdd(&partial[(blockIdx.x & (NBIN - 1)) * HH + tid], t);
  }
}

// ---------------------------------------------------------------------------
// Kernel 5: final head: p = sum partial bins; tanh(p@Wf1+bf1)@Wf2+bf2 -> out
// (round-8 exact)
// ---------------------------------------------------------------------------
__global__ __launch_bounds__(64) void k_final(const float* __restrict__ partial,
    const float* __restrict__ Wf1, const float* __restrict__ bf1,
    const float* __restrict__ Wf2, const float* __restrict__ bf2,
    float* __restrict__ out) {
  __shared__ float sp[HH];
  const int lane = threadIdx.x;
  if (lane < HH) {
    float s = 0.f;
    for (int bb = 0; bb < NBIN; ++bb) s += partial[bb * HH + lane];
    sp[lane] = s;
  }
  __syncthreads();
  float q = bf1[lane];
  for (int f = 0; f < HH; ++f) q += sp[f] * Wf1[f * 64 + lane];
  q = tanhf(q);
  float rsum = q * Wf2[lane];
  for (int off = 32; off; off >>= 1) rsum += __shfl_xor(rsum, off);
  if (lane == 0) out[0] = rsum + bf2[0];
}

// ---------------------------------------------------------------------------
extern "C" void kernel_launch(void* const* d_in, const int* in_sizes, int n_in,
                              void* d_out, int out_size, void* d_ws, size_t ws_size,
                              hipStream_t stream) {
  const float* x   = (const float*)d_in[0];
  const float* a   = (const float*)d_in[1];
  const float* W1  = (const float*)d_in[2];
  const float* b1  = (const float*)d_in[3];
  const float* W2  = (const float*)d_in[4];
  const float* b2  = (const float*)d_in[5];
  const float* W3  = (const float*)d_in[6];
  const float* b3  = (const float*)d_in[7];
  const float* Wf1 = (const float*)d_in[8];
  const float* bf1 = (const float*)d_in[9];
  const float* Wf2 = (const float*)d_in[10];
  const float* bf2 = (const float*)d_in[11];

  char* ws = (char*)d_ws;
  unsigned short* adj = (unsigned short*)ws;  ws += (size_t)NN * CAP * sizeof(unsigned short); // 2.30 MB
  int*   deg     = (int*)ws;                  ws += (size_t)((NN * sizeof(int) + 255) & ~(size_t)255);
  float* Zb      = (float*)ws;                ws += (size_t)NN * HH * sizeof(float);
  float* Yb      = (float*)ws;                ws += (size_t)NN * HH * sizeof(float);
  float* h1      = (float*)ws;                ws += (size_t)NN * HH * sizeof(float);
  float* h2      = (float*)ws;                ws += (size_t)NN * HH * sizeof(float);
  float* partial = (float*)ws;                // NBIN*32 floats

  hipLaunchKernelGGL(k_scanx,  dim3(NN + NB4), dim3(256), 0, stream,
                     a, x, W1, adj, deg, Zb, Yb, partial);
  hipLaunchKernelGGL(k_gl1,    dim3(NB4), dim3(256), 0, stream, Zb, Yb, b1, adj, deg, h1);
  hipLaunchKernelGGL(k_sageh,  dim3(NB4), dim3(256), 0, stream, h1, W2, b2, adj, deg, h2);
  hipLaunchKernelGGL(k_sageh3, dim3(NB4), dim3(256), 0, stream, h2, W3, b3, adj, deg, partial);
  hipLaunchKernelGGL(k_final,  dim3(1),   dim3(64),  0, stream, partial, Wf1, bf1, Wf2, bf2, (float*)d_out);
}